// Round 8
// baseline (497.240 us; speedup 1.0000x reference)
//
#include <hip/hip_runtime.h>
#include <hip/hip_bf16.h>

// Problem constants
#define BB 8
#define MELN 64
#define TSN 512
#define HHN 128
#define CCN 20

// ws layout (float offsets)
#define OFF_WINT  0                          // W_in^T [64][128]
#define OFF_WT    8192                       // 5x [128][128] transposed f32: ii,if,ig,io,xo
#define OFF_WQ16  (OFF_WT + 5*16384)         // [64][128] u32: pk2(WqT[2p][r], WqT[2p+1][r])
#define OFF_WH16  (OFF_WT + 6*16384)         // [4][64][128] u32 (occupies slots 6,7)
#define OFF_FLAG  (OFF_WT + 8*16384)         // int[8*128] chunk flags + int[8] done counters (dead slot 8)
#define OFF_RS    (OFF_WT + 10*16384)        // [128][4] rowsums of W_hi,W_hf,W_hg,W_ho
#define OFF_XPRE  (OFF_RS + 512)             // [B][T][128 rows][4 gates] x-terms (+both biases) f32
#define OFF_AQ    (OFF_XPRE + BB*TSN*512)    // [B][T][128] a = q/sqrt(H) f32
#define OFF_HALL  (OFF_AQ + BB*TSN*128)      // [B][T][128] h_t f32
#define OFF_APRE  (OFF_HALL + BB*TSN*128)    // [B][T][128] uint4: 4x pk2(A1_g, A2_g) f16
// total floats = OFF_APRE + BB*TSN*128*2 = 5,415,424 (~20.7 MB)

typedef _Float16 hf2 __attribute__((ext_vector_type(2)));

__device__ __forceinline__ float rcp_f(float x) { return __builtin_amdgcn_rcpf(x); }
__device__ __forceinline__ float sigm_f(float x) { return rcp_f(1.0f + __expf(-x)); }
__device__ __forceinline__ float tanh_f(float x) { return fmaf(2.0f, rcp_f(1.0f + __expf(-2.0f * x)), -1.0f); }
__device__ __forceinline__ float sigm_p(float x) { return 1.0f / (1.0f + __expf(-x)); }

#if __has_builtin(__builtin_amdgcn_fdot2)
__device__ __forceinline__ float dot2f(hf2 a, hf2 b, float c) {
  return __builtin_amdgcn_fdot2(a, b, c, false);
}
#else
__device__ __forceinline__ float dot2f(hf2 a, hf2 b, float c) {
  return fmaf((float)a.x, (float)b.x, fmaf((float)a.y, (float)b.y, c));
}
#endif

__device__ __forceinline__ hf2 mk2(float a, float b) {
  hf2 v; v.x = (_Float16)a; v.y = (_Float16)b; return v;
}
__device__ __forceinline__ unsigned pk2(float a, float b) {
  return __builtin_bit_cast(unsigned, __builtin_amdgcn_cvt_pkrtz(a, b));
}
__device__ __forceinline__ unsigned mku(float a, float b) {
  return __builtin_bit_cast(unsigned, mk2(a, b));   // RTE pack (2x cvt)
}
__device__ __forceinline__ hf2 u2h(unsigned u) { return __builtin_bit_cast(hf2, u); }

// ---- wave-64 sum: DPP (VALU-pipe) with shfl fallback. Result valid in lane 63. ----
#if __has_builtin(__builtin_amdgcn_update_dpp)
template <int CTRL>
__device__ __forceinline__ float dppadd(float x) {
  int v = __builtin_amdgcn_update_dpp(0, __builtin_bit_cast(int, x), CTRL, 0xf, 0xf, true);
  return x + __builtin_bit_cast(float, v);
}
__device__ __forceinline__ float wsum64(float x) {
  x = dppadd<0x111>(x);   // row_shr:1
  x = dppadd<0x112>(x);   // row_shr:2
  x = dppadd<0x114>(x);   // row_shr:4
  x = dppadd<0x118>(x);   // row_shr:8  -> lane15 of each 16-row has row sum
  x = dppadd<0x142>(x);   // row_bcast:15 -> lane31/63 have 32-lane sums
  x = dppadd<0x143>(x);   // row_bcast:31 -> lane63 has 64-lane sum
  return x;
}
#else
__device__ __forceinline__ float wsum64(float x) {
  x += __shfl_xor(x, 1);  x += __shfl_xor(x, 2);  x += __shfl_xor(x, 4);
  x += __shfl_xor(x, 8);  x += __shfl_xor(x, 16); x += __shfl_xor(x, 32);
  return x;
}
#endif

// ---- lgkm-only workgroup barrier (does NOT drain vmcnt; rule #18 fences) ----
__device__ __forceinline__ void ldsbar() {
  __builtin_amdgcn_sched_barrier(0);
  asm volatile("s_waitcnt lgkmcnt(0)" ::: "memory");
  __builtin_amdgcn_s_barrier();
  __builtin_amdgcn_sched_barrier(0);
}

// ---------------- P0: weight prep + flag zeroing ----------------
__global__ void k_prep(const float* __restrict__ W_in, const float* __restrict__ W_ii,
                       const float* __restrict__ W_if, const float* __restrict__ W_ig,
                       const float* __restrict__ W_io, const float* __restrict__ W_xo,
                       const float* __restrict__ W_q,  const float* __restrict__ W_hi,
                       const float* __restrict__ W_hf, const float* __restrict__ W_hg,
                       const float* __restrict__ W_ho, float* __restrict__ ws) {
  int m = blockIdx.x;  // 0..12
  if (m == 12) {       // zero producer-consumer flags (re-zeroed every graph replay)
    int* fl = (int*)(ws + OFF_FLAG);
    for (int idx = threadIdx.x; idx < 8 * 128 + 8; idx += blockDim.x) fl[idx] = 0;
    return;
  }
  if (m == 11) {
    for (int idx = threadIdx.x; idx < 512; idx += blockDim.x) {
      int g = idx >> 7, r = idx & 127;
      const float* W = (g == 0) ? W_hi : (g == 1) ? W_hf : (g == 2) ? W_hg : W_ho;
      float s = 0.f;
      for (int c = 0; c < 128; ++c) s += W[r * 128 + c];
      ws[OFF_RS + r * 4 + g] = s;
    }
    return;
  }
  if (m == 0) {
    for (int idx = threadIdx.x; idx < 128 * 64; idx += blockDim.x) {
      int r = idx >> 6, c = idx & 63;
      ws[OFF_WINT + c * 128 + r] = W_in[idx];
    }
    return;
  }
  const float* s[10] = {W_ii, W_if, W_ig, W_io, W_xo, W_q, W_hi, W_hf, W_hg, W_ho};
  const float* src = s[m - 1];
  if (m <= 5) {   // f32 transpose: dst[c][r] = W[r][c]
    float* dst = ws + OFF_WT + (size_t)(m - 1) * 16384;
    for (int idx = threadIdx.x; idx < 16384; idx += blockDim.x) {
      int r = idx >> 7, c = idx & 127;
      dst[c * 128 + r] = src[idx];
    }
  } else {        // f16-pair pack along contraction axis: dst[p][r] = (W[r][2p], W[r][2p+1])
    unsigned* dst = (m == 6)
        ? (unsigned*)(ws + OFF_WQ16)
        : (unsigned*)(ws + OFF_WH16) + (size_t)(m - 7) * 8192;
    for (int idx = threadIdx.x; idx < 8192; idx += blockDim.x) {
      int p = idx >> 7, r = idx & 127;
      dst[p * 128 + r] = mku(src[r * 128 + 2 * p], src[r * 128 + 2 * p + 1]);
    }
  }
}

// ---------------- P1: FUSED xproj (producer) + scan (consumer) ----------------
// Blocks 0..1023: xproj role for (b = bid&7, chunk = bid>>3) -> 4 t's, chunk-major
// so low-t chunks across all batches complete first (matches consumption order).
// Blocks 1024..1031: scan role for batch bid-1024; spin-waits on per-chunk flags
// only until done[b]==128 is observed, then runs the proven 357us steady state
// with zero extra synchronization.
__global__ __launch_bounds__(128, 1)
void k_main(const float* __restrict__ x,
            const float* __restrict__ b_in,
            const float* __restrict__ b_ii, const float* __restrict__ b_hi,
            const float* __restrict__ b_if, const float* __restrict__ b_hf,
            const float* __restrict__ b_ig, const float* __restrict__ b_hg,
            const float* __restrict__ b_io, const float* __restrict__ b_ho,
            const float* __restrict__ b_xo, const float* __restrict__ b_q,
            const float* __restrict__ W_k,  const float* __restrict__ b_k,
            const float* __restrict__ W_v,  const float* __restrict__ b_v,
            const float* __restrict__ W_ao, const float* __restrict__ b_ao,
            float* __restrict__ ws) {
  const int bid = blockIdx.x;
  const int tid = threadIdx.x;
  int* flagA = (int*)(ws + OFF_FLAG);      // [8][128] chunk flags
  int* doneC = flagA + 8 * 128;            // [8] per-batch completion counters

  if (bid < BB * 128) {
    // ================= xproj role =================
    const int b  = bid & 7;
    const int t0 = (bid >> 3) * 4;

    __shared__ __align__(16) float xsT[MELN * 4];
    __shared__ __align__(16) float xpsT[128 * 4];
    __shared__ __align__(16) float xosT[128 * 4];
    __shared__ __align__(16) unsigned xo16[64 * 4];
    __shared__ __align__(16) unsigned ap16[64 * 4];
    __shared__ __align__(16) unsigned as16[64 * 4];

    const float* WinT = ws + OFF_WINT;
    const float* WT   = ws + OFF_WT;
    float* Xpre = ws + OFF_XPRE;
    float* aq   = ws + OFF_AQ;

    #pragma unroll
    for (int k = 0; k < 2; ++k) {
      int idx = k * 128 + tid;
      int mm = idx >> 2, tt = idx & 3;
      xsT[mm * 4 + tt] = x[((size_t)b * MELN + mm) * TSN + t0 + tt];
    }
    __syncthreads();

    float acc4[4];
    {
      float bi = b_in[tid];
      #pragma unroll
      for (int j = 0; j < 4; ++j) acc4[j] = bi;
    }
    #pragma unroll 2
    for (int mI = 0; mI < MELN; ++mI) {
      float w = WinT[mI * 128 + tid];
      float4 xa = *(const float4*)&xsT[mI * 4];
      acc4[0] = fmaf(w, xa.x, acc4[0]); acc4[1] = fmaf(w, xa.y, acc4[1]);
      acc4[2] = fmaf(w, xa.z, acc4[2]); acc4[3] = fmaf(w, xa.w, acc4[3]);
    }
    *(float4*)&xpsT[tid * 4] = make_float4(acc4[0], acc4[1], acc4[2], acc4[3]);
    __syncthreads();

    float accg[5][4];
    {
      float bsum[5];
      bsum[0] = b_ii[tid] + b_hi[tid];
      bsum[1] = b_if[tid] + b_hf[tid];
      bsum[2] = b_ig[tid] + b_hg[tid];
      bsum[3] = b_io[tid] + b_ho[tid];
      bsum[4] = b_xo[tid];
      #pragma unroll
      for (int g = 0; g < 5; ++g)
        #pragma unroll
        for (int j = 0; j < 4; ++j) accg[g][j] = bsum[g];
    }
    #pragma unroll 2
    for (int c = 0; c < 128; ++c) {
      const float4 xa = *(const float4*)&xpsT[c * 4];
      #pragma unroll
      for (int g = 0; g < 5; ++g) {
        const float w = WT[g * 16384 + c * 128 + tid];
        accg[g][0] = fmaf(w, xa.x, accg[g][0]);
        accg[g][1] = fmaf(w, xa.y, accg[g][1]);
        accg[g][2] = fmaf(w, xa.z, accg[g][2]);
        accg[g][3] = fmaf(w, xa.w, accg[g][3]);
      }
    }
    {
      size_t base = ((size_t)b * TSN + t0) * 512;
      #pragma unroll
      for (int tt = 0; tt < 4; ++tt)
        *(float4*)&Xpre[base + (size_t)tt * 512 + tid * 4] =
            make_float4(accg[0][tt], accg[1][tt], accg[2][tt], accg[3][tt]);
    }
    {
      #pragma unroll
      for (int tt = 0; tt < 4; ++tt) xosT[tid * 4 + tt] = sigm_p(accg[4][tt]);
    }
    __syncthreads();

    {
      const int p = tid & 63;
      const int th = (tid >> 6) * 2;
      #pragma unroll
      for (int j = 0; j < 2; ++j) {
        const int tt = th + j;
        xo16[p * 4 + tt] = mku(xosT[(2 * p) * 4 + tt], xosT[(2 * p + 1) * 4 + tt]);
      }
    }
    __syncthreads();

    float accq[4];
    {
      float bq = b_q[tid];
      #pragma unroll
      for (int j = 0; j < 4; ++j) accq[j] = bq;
    }
    const unsigned* WQ = (const unsigned*)(ws + OFF_WQ16);
    #pragma unroll 2
    for (int p = 0; p < 64; ++p) {
      const hf2 wq = u2h(WQ[p * 128 + tid]);
      const uint4 xa = *(const uint4*)&xo16[p * 4];
      accq[0] = dot2f(wq, u2h(xa.x), accq[0]);
      accq[1] = dot2f(wq, u2h(xa.y), accq[1]);
      accq[2] = dot2f(wq, u2h(xa.z), accq[2]);
      accq[3] = dot2f(wq, u2h(xa.w), accq[3]);
    }
    float av[4];
    #pragma unroll
    for (int tt = 0; tt < 4; ++tt) {
      av[tt] = accq[tt] * 0.08838834764831845f;
      aq[((size_t)b * TSN + t0 + tt) * 128 + tid] = av[tt];
    }

    __syncthreads();
    *(float4*)&xpsT[tid * 4] = make_float4(av[0], av[1], av[2], av[3]);
    __syncthreads();
    {
      const int p = tid & 63;
      const int th = (tid >> 6) * 2;
      #pragma unroll
      for (int j = 0; j < 2; ++j) {
        const int tt = th + j;
        const float a0 = xpsT[(2 * p) * 4 + tt];
        const float a1 = xpsT[(2 * p + 1) * 4 + tt];
        ap16[p * 4 + tt] = mku(a0, a1);
        as16[p * 4 + tt] = mku(a0 * a0, a1 * a1);
      }
    }
    __syncthreads();
    float accA[4][4], accB[4][4];
    #pragma unroll
    for (int g = 0; g < 4; ++g)
      #pragma unroll
      for (int j = 0; j < 4; ++j) { accA[g][j] = 0.f; accB[g][j] = 0.f; }
    const unsigned* WH = (const unsigned*)(ws + OFF_WH16);
    #pragma unroll 2
    for (int p = 0; p < 64; ++p) {
      const uint4 aa = *(const uint4*)&ap16[p * 4];
      const uint4 sa = *(const uint4*)&as16[p * 4];
      #pragma unroll
      for (int g = 0; g < 4; ++g) {
        const hf2 w = u2h(WH[g * 8192 + p * 128 + tid]);
        accA[g][0] = dot2f(w, u2h(aa.x), accA[g][0]);
        accA[g][1] = dot2f(w, u2h(aa.y), accA[g][1]);
        accA[g][2] = dot2f(w, u2h(aa.z), accA[g][2]);
        accA[g][3] = dot2f(w, u2h(aa.w), accA[g][3]);
        accB[g][0] = dot2f(w, u2h(sa.x), accB[g][0]);
        accB[g][1] = dot2f(w, u2h(sa.y), accB[g][1]);
        accB[g][2] = dot2f(w, u2h(sa.z), accB[g][2]);
        accB[g][3] = dot2f(w, u2h(sa.w), accB[g][3]);
      }
    }
    {
      uint4* APre4 = (uint4*)(ws + OFF_APRE);
      #pragma unroll
      for (int tt = 0; tt < 4; ++tt) {
        uint4 u;
        u.x = pk2(accA[0][tt], accB[0][tt]);
        u.y = pk2(accA[1][tt], accB[1][tt]);
        u.z = pk2(accA[2][tt], accB[2][tt]);
        u.w = pk2(accA[3][tt], accB[3][tt]);
        APre4[((size_t)b * TSN + t0 + tt) * 128 + tid] = u;
      }
    }
    // -------- publish: release own stores, sync, thread0 sets flag --------
    __threadfence();
    __syncthreads();
    if (tid == 0) {
      __hip_atomic_store(&flagA[b * 128 + (bid >> 3)], 1,
                         __ATOMIC_RELEASE, __HIP_MEMORY_SCOPE_AGENT);
      atomicAdd(&doneC[b], 1);
    }
    return;
  }

  // ================= scan role =================
  const int lane = tid & 63;
  const int wid  = tid >> 6;
  const int b    = bid - BB * 128;

  __shared__ __align__(16) _Float16 ch[128];
  __shared__ __align__(16) float part[16];
  __shared__ int rdyLds;

  int readyAll = 0;
  // Wait until chunk k of batch b is published (only active until done[b]==128
  // observed once; afterwards a pure register test -> zero steady-state cost).
  auto waitChunk = [&](int k) {
    if (readyAll) return;
    if (tid == 0) {
      int all = (__hip_atomic_load(&doneC[b], __ATOMIC_RELAXED,
                                   __HIP_MEMORY_SCOPE_AGENT) == 128);
      if (!all) {
        while (__hip_atomic_load(&flagA[b * 128 + k], __ATOMIC_RELAXED,
                                 __HIP_MEMORY_SCOPE_AGENT) == 0)
          __builtin_amdgcn_s_sleep(8);
      }
      rdyLds = all;
    }
    __syncthreads();
    readyAll = rdyLds;
    __threadfence();   // acquire: make producer stores visible before data reads
  };

  hf2 wkk2[64];
  #pragma unroll
  for (int p = 0; p < 64; ++p)
    wkk2[p] = mk2(W_k[(size_t)tid * 128 + 2 * p], W_k[(size_t)tid * 128 + 2 * p + 1]);
  const float bkr = b_k[tid];
  const float4 RSv = *(const float4*)&ws[OFF_RS + tid * 4];

  float s1 = 0.f, s2 = 0.f;
  for (int j = 0; j < 128; ++j) {
    s1 = fmaf(W_ao[j], W_v[j], s1);
    s2 = fmaf(W_ao[j], b_v[j], s2);
  }
  s2 += b_ao[0];
  const float inv128 = 0.0078125f;
  const float s1i = s1 * inv128;

  const float* Xb = ws + OFF_XPRE + (size_t)b * TSN * 512;
  const float* ab = ws + OFF_AQ   + (size_t)b * TSN * 128;
  float*       Hb = ws + OFF_HALL + (size_t)b * TSN * 128;
  const uint4* APb = (const uint4*)(ws + OFF_APRE) + (size_t)b * TSN * 128;

  const uint4* c4u = (const uint4*)ch;

  waitChunk(0);   // prologue reads t=0,1 and APb[0]

  float4 X4e = *(const float4*)&Xb[tid * 4];                    // t=0
  float4 X4o = *(const float4*)&Xb[512 + tid * 4];              // t=1
  float  are = ab[tid];                                         // t=0
  float  aro = ab[128 + tid];                                   // t=1
  uint4  Ae  = APb[tid];   // dummy finite (t=0 has gamma=0)
  uint4  Ao  = APb[tid];   // A slot 0, used at t=1

  float c_reg = 0.f;
  float g0 = 0.f;
  hf2   g12 = u2h(0u);

#define SCAN_STEP(T, X4v, arv, Argv)                                          \
  {                                                                           \
    const float pi = dot2f(u2h((Argv).x), g12, fmaf(g0, RSv.x, (X4v).x));     \
    const float pf = dot2f(u2h((Argv).y), g12, fmaf(g0, RSv.y, (X4v).y));     \
    const float pg = dot2f(u2h((Argv).z), g12, fmaf(g0, RSv.z, (X4v).z));     \
    const float po = dot2f(u2h((Argv).w), g12, fmaf(g0, RSv.w, (X4v).w));     \
    /* early prefetch into this parity's regs (X,A last used above) */        \
    {                                                                         \
      const int tx = ((T) + 2 < TSN) ? (T) + 2 : TSN - 1;                     \
      (X4v) = *(const float4*)&Xb[(size_t)tx * 512 + tid * 4];                \
      const int ta = ((T) + 1 < TSN) ? (T) + 1 : TSN - 1;                     \
      (Argv) = APb[(size_t)ta * 128 + tid];                                   \
    }                                                                         \
    const float gi = sigm_f(pi);                                              \
    const float gf = sigm_f(pf);                                              \
    const float gg = tanh_f(pg);                                              \
    const float go = sigm_f(po);                                              \
    c_reg = fmaf(gf, c_reg, gi * gg);                                         \
    ch[tid] = (_Float16)c_reg;                                                \
    ldsbar();  /* [1] c visible (lgkm-only) */                                \
    float ka0 = 0.f, ka1 = 0.f, ka2 = 0.f, ka3 = 0.f;                         \
    _Pragma("unroll")                                                         \
    for (int u = 0; u < 16; ++u) {                                            \
      const uint4 cv = c4u[u];                                                \
      ka0 = dot2f(wkk2[u * 4 + 0], u2h(cv.x), ka0);                           \
      ka1 = dot2f(wkk2[u * 4 + 1], u2h(cv.y), ka1);                           \
      ka2 = dot2f(wkk2[u * 4 + 2], u2h(cv.z), ka2);                           \
      ka3 = dot2f(wkk2[u * 4 + 3], u2h(cv.w), ka3);                           \
    }                                                                         \
    const float kr = ((ka0 + ka1) + (ka2 + ka3)) + bkr;                       \
    const float kp2 = kr * kr;                                                \
    float m0 = kr, m1 = go, m2 = kp2, m3 = go * kr, m4 = go * kp2;            \
    m0 = wsum64(m0); m1 = wsum64(m1); m2 = wsum64(m2);                        \
    m3 = wsum64(m3); m4 = wsum64(m4);                                         \
    if (lane == 63) {                                                         \
      part[wid * 8 + 0] = m0; part[wid * 8 + 1] = m1;                         \
      part[wid * 8 + 2] = m2; part[wid * 8 + 3] = m3;                         \
      part[wid * 8 + 4] = m4;                                                 \
    }                                                                         \
    ldsbar();  /* [2] partials visible (lgkm-only) */                         \
    const float4 pa = *(const float4*)&part[0];                               \
    const float4 pb = *(const float4*)&part[8];                               \
    const float D1 = pa.x + pb.x;                                             \
    const float N0 = pa.y + pb.y;                                             \
    const float D2 = pa.z + pb.z;                                             \
    const float N1 = pa.w + pb.w;                                             \
    const float N2 = part[4] + part[12];                                      \
    const float t1 = D1 * inv128;                                             \
    g0 = fmaf(s1i, N0, s2);                                                   \
    const float gm1 = s1i * (N1 - N0 * t1);                                   \
    const float gm2 = s1i * (0.5f * N2 - (N1 * D1 + 0.5f * N0 * D2) * inv128  \
                             + N0 * t1 * t1);                                 \
    const float hn = fmaf(fmaf(gm2, (arv), gm1), (arv), g0);                  \
    Hb[(size_t)(T) * 128 + tid] = hn;                                         \
    g12 = u2h(pk2(gm1, gm2));                                                 \
    /* ar prefetch (distance-2, after last use) */                            \
    {                                                                         \
      const int tr = ((T) + 2 < TSN) ? (T) + 2 : TSN - 1;                     \
      (arv) = ab[(size_t)tr * 128 + tid];                                     \
    }                                                                         \
  }

  // 128 chunks of 4 steps; prefetch at step 4k+3 reaches t=4k+5 (chunk k+1),
  // so chunk k+1 must be published before chunk k's steps run.
  for (int kk = 0; kk < TSN / 4; ++kk) {
    waitChunk(kk + 1 < 128 ? kk + 1 : 127);
    SCAN_STEP(4 * kk,     X4e, are, Ae);
    SCAN_STEP(4 * kk + 1, X4o, aro, Ao);
    SCAN_STEP(4 * kk + 2, X4e, are, Ae);
    SCAN_STEP(4 * kk + 3, X4o, aro, Ao);
  }
#undef SCAN_STEP
}

// ---------------- P3: y = Hall @ W_out^T + b_out -> fp32 (B,C,T) ----------------
__global__ __launch_bounds__(256)
void k_out(const float* __restrict__ W_out, const float* __restrict__ b_out,
           const float* __restrict__ ws, float* __restrict__ out) {
  const int tid = threadIdx.x;
  const int b  = blockIdx.x >> 3;
  const int t0 = (blockIdx.x & 7) * 64;

  // stride 129 (odd): conflict-free read pattern
  __shared__ float Hs[64 * 129];

  const float* Hb = ws + OFF_HALL + ((size_t)b * TSN + t0) * 128;
  for (int k = 0; k < 32; ++k) {
    const int idx = k * 256 + tid;
    Hs[(idx >> 7) * 129 + (idx & 127)] = Hb[idx];
  }
  __syncthreads();

  const int tt = tid & 63;
  const int c0 = (tid >> 6) * 5;
  for (int j = 0; j < 5; ++j) {
    const int c = c0 + j;
    float s = b_out[c];
    for (int i = 0; i < 128; ++i)
      s = fmaf(Hs[tt * 129 + i], W_out[c * 128 + i], s);
    out[((size_t)b * CCN + c) * TSN + t0 + tt] = s;
  }
}

extern "C" void kernel_launch(void* const* d_in, const int* in_sizes, int n_in,
                              void* d_out, int out_size, void* d_ws, size_t ws_size,
                              hipStream_t stream) {
  const float* x    = (const float*)d_in[0];
  const float* W_in = (const float*)d_in[1];
  const float* b_in = (const float*)d_in[2];
  const float* W_out= (const float*)d_in[3];
  const float* b_out= (const float*)d_in[4];
  const float* W_ii = (const float*)d_in[5];
  const float* b_ii = (const float*)d_in[6];
  const float* W_hi = (const float*)d_in[7];
  const float* b_hi = (const float*)d_in[8];
  const float* W_if = (const float*)d_in[9];
  const float* b_if = (const float*)d_in[10];
  const float* W_hf = (const float*)d_in[11];
  const float* b_hf = (const float*)d_in[12];
  const float* W_ig = (const float*)d_in[13];
  const float* b_ig = (const float*)d_in[14];
  const float* W_hg = (const float*)d_in[15];
  const float* b_hg = (const float*)d_in[16];
  const float* W_io = (const float*)d_in[17];
  const float* b_io = (const float*)d_in[18];
  const float* W_ho = (const float*)d_in[19];
  const float* b_ho = (const float*)d_in[20];
  const float* W_xo = (const float*)d_in[21];
  const float* b_xo = (const float*)d_in[22];
  const float* W_q  = (const float*)d_in[23];
  const float* b_q  = (const float*)d_in[24];
  const float* W_k  = (const float*)d_in[25];
  const float* b_k  = (const float*)d_in[26];
  const float* W_v  = (const float*)d_in[27];
  const float* b_v  = (const float*)d_in[28];
  const float* W_ao = (const float*)d_in[29];
  const float* b_ao = (const float*)d_in[30];

  float* ws = (float*)d_ws;
  float* out = (float*)d_out;

  k_prep<<<13, 256, 0, stream>>>(W_in, W_ii, W_if, W_ig, W_io, W_xo, W_q,
                                 W_hi, W_hf, W_hg, W_ho, ws);
  k_main<<<BB * 128 + BB, 128, 0, stream>>>(x, b_in, b_ii, b_hi, b_if, b_hf,
                                            b_ig, b_hg, b_io, b_ho, b_xo, b_q,
                                            W_k, b_k, W_v, b_v, W_ao, b_ao, ws);
  k_out<<<BB * 8, 256, 0, stream>>>(W_out, b_out, ws, out);
}

// Round 9
// 455.969 us; speedup vs baseline: 1.0905x; 1.0905x over previous
//
#include <hip/hip_runtime.h>
#include <hip/hip_bf16.h>

// Problem constants
#define BB 8
#define MELN 64
#define TSN 512
#define HHN 128
#define CCN 20

// ws layout (float offsets)
#define OFF_WINT  0                          // W_in^T [64][128]
#define OFF_WT    8192                       // 5x [128][128] transposed f32: ii,if,ig,io,xo
#define OFF_WQ16  (OFF_WT + 5*16384)         // [64][128] u32: pk2(WqT[2p][r], WqT[2p+1][r])
#define OFF_WH16  (OFF_WT + 6*16384)         // [4][64][128] u32: same packing for hi,hf,hg,ho
#define OFF_RS    (OFF_WT + 10*16384)        // [128][4] rowsums of W_hi,W_hf,W_hg,W_ho
#define OFF_XPRE  (OFF_RS + 512)             // [B][T][128 rows][4 gates] x-terms (+both biases) f32
#define OFF_AQ    (OFF_XPRE + BB*TSN*512)    // [B][T][128] a = q/sqrt(H) f32
#define OFF_HALL  (OFF_AQ + BB*TSN*128)      // [B][T][128] h_t f32
#define OFF_APRE  (OFF_HALL + BB*TSN*128)    // [B][T][128] uint4: 4x pk2(A1_g, A2_g) f16
// total floats = OFF_APRE + BB*TSN*128*2 = 5,415,424 (~20.7 MB)

typedef _Float16 hf2 __attribute__((ext_vector_type(2)));

__device__ __forceinline__ float rcp_f(float x) { return __builtin_amdgcn_rcpf(x); }
__device__ __forceinline__ float sigm_f(float x) { return rcp_f(1.0f + __expf(-x)); }
__device__ __forceinline__ float tanh_f(float x) { return fmaf(2.0f, rcp_f(1.0f + __expf(-2.0f * x)), -1.0f); }
__device__ __forceinline__ float sigm_p(float x) { return 1.0f / (1.0f + __expf(-x)); }

#if __has_builtin(__builtin_amdgcn_fdot2)
__device__ __forceinline__ float dot2f(hf2 a, hf2 b, float c) {
  return __builtin_amdgcn_fdot2(a, b, c, false);
}
#else
__device__ __forceinline__ float dot2f(hf2 a, hf2 b, float c) {
  return fmaf((float)a.x, (float)b.x, fmaf((float)a.y, (float)b.y, c));
}
#endif

__device__ __forceinline__ hf2 mk2(float a, float b) {
  hf2 v; v.x = (_Float16)a; v.y = (_Float16)b; return v;
}
__device__ __forceinline__ unsigned pk2(float a, float b) {
  return __builtin_bit_cast(unsigned, __builtin_amdgcn_cvt_pkrtz(a, b));
}
__device__ __forceinline__ unsigned mku(float a, float b) {
  return __builtin_bit_cast(unsigned, mk2(a, b));   // RTE pack (2x cvt)
}
__device__ __forceinline__ hf2 u2h(unsigned u) { return __builtin_bit_cast(hf2, u); }

// ---- wave-64 sum: DPP (VALU-pipe) with shfl fallback. Result valid in lane 63. ----
#if __has_builtin(__builtin_amdgcn_update_dpp)
template <int CTRL>
__device__ __forceinline__ float dppadd(float x) {
  int v = __builtin_amdgcn_update_dpp(0, __builtin_bit_cast(int, x), CTRL, 0xf, 0xf, true);
  return x + __builtin_bit_cast(float, v);
}
__device__ __forceinline__ float wsum64(float x) {
  x = dppadd<0x111>(x);   // row_shr:1
  x = dppadd<0x112>(x);   // row_shr:2
  x = dppadd<0x114>(x);   // row_shr:4
  x = dppadd<0x118>(x);   // row_shr:8  -> lane15 of each 16-row has row sum
  x = dppadd<0x142>(x);   // row_bcast:15 -> lane31/63 have 32-lane sums
  x = dppadd<0x143>(x);   // row_bcast:31 -> lane63 has 64-lane sum
  return x;
}
#else
__device__ __forceinline__ float wsum64(float x) {
  x += __shfl_xor(x, 1);  x += __shfl_xor(x, 2);  x += __shfl_xor(x, 4);
  x += __shfl_xor(x, 8);  x += __shfl_xor(x, 16); x += __shfl_xor(x, 32);
  return x;
}
#endif

// ---- lgkm-only workgroup barrier: does NOT drain vmcnt, so in-flight global
// prefetch loads survive across it. sched_barrier(0) pins LDS ops (rule #18).
__device__ __forceinline__ void ldsbar() {
  __builtin_amdgcn_sched_barrier(0);
  asm volatile("s_waitcnt lgkmcnt(0)" ::: "memory");
  __builtin_amdgcn_s_barrier();
  __builtin_amdgcn_sched_barrier(0);
}

// ---------------- P0: weight prep ----------------
// m==0: W_in transpose. m 1..5: transpose ii,if,ig,io,xo (f32).
// m==6: W_q -> f16-pair pack. m 7..10: W_hi..W_ho -> f16-pair pack. m==11: rowsums.
__global__ void k_prep(const float* __restrict__ W_in, const float* __restrict__ W_ii,
                       const float* __restrict__ W_if, const float* __restrict__ W_ig,
                       const float* __restrict__ W_io, const float* __restrict__ W_xo,
                       const float* __restrict__ W_q,  const float* __restrict__ W_hi,
                       const float* __restrict__ W_hf, const float* __restrict__ W_hg,
                       const float* __restrict__ W_ho, float* __restrict__ ws) {
  int m = blockIdx.x;  // 0..11
  if (m == 11) {
    for (int idx = threadIdx.x; idx < 512; idx += blockDim.x) {
      int g = idx >> 7, r = idx & 127;
      const float* W = (g == 0) ? W_hi : (g == 1) ? W_hf : (g == 2) ? W_hg : W_ho;
      float s = 0.f;
      for (int c = 0; c < 128; ++c) s += W[r * 128 + c];
      ws[OFF_RS + r * 4 + g] = s;
    }
    return;
  }
  if (m == 0) {
    for (int idx = threadIdx.x; idx < 128 * 64; idx += blockDim.x) {
      int r = idx >> 6, c = idx & 63;
      ws[OFF_WINT + c * 128 + r] = W_in[idx];
    }
    return;
  }
  const float* s[10] = {W_ii, W_if, W_ig, W_io, W_xo, W_q, W_hi, W_hf, W_hg, W_ho};
  const float* src = s[m - 1];
  if (m <= 5) {   // f32 transpose: dst[c][r] = W[r][c]
    float* dst = ws + OFF_WT + (size_t)(m - 1) * 16384;
    for (int idx = threadIdx.x; idx < 16384; idx += blockDim.x) {
      int r = idx >> 7, c = idx & 127;
      dst[c * 128 + r] = src[idx];
    }
  } else {        // f16-pair pack along the contraction axis: dst[p][r] = (W[r][2p], W[r][2p+1])
    unsigned* dst = (m == 6)
        ? (unsigned*)(ws + OFF_WQ16)
        : (unsigned*)(ws + OFF_WH16) + (size_t)(m - 7) * 8192;
    for (int idx = threadIdx.x; idx < 8192; idx += blockDim.x) {
      int p = idx >> 7, r = idx & 127;
      dst[p * 128 + r] = mku(src[r * 128 + 2 * p], src[r * 128 + 2 * p + 1]);
    }
  }
}

// ---------------- P1: x-side projections + A-moment precompute.
// 4 t's per block, 1024 blocks -> 4 blocks/CU (8 waves/CU) for latency hiding.
// Gate x-terms full f32; q-projection and A-moments in f16-pair dot2. ----
__global__ __launch_bounds__(128)
void k_xproj(const float* __restrict__ x,
             const float* __restrict__ b_in,
             const float* __restrict__ b_ii, const float* __restrict__ b_hi,
             const float* __restrict__ b_if, const float* __restrict__ b_hf,
             const float* __restrict__ b_ig, const float* __restrict__ b_hg,
             const float* __restrict__ b_io, const float* __restrict__ b_ho,
             const float* __restrict__ b_xo, const float* __restrict__ b_q,
             float* __restrict__ ws) {
  const int tid = threadIdx.x;
  const int b  = blockIdx.x >> 7;            // 0..7
  const int t0 = (blockIdx.x & 127) * 4;     // 0..508

  __shared__ __align__(16) float xsT[MELN * 4];     // [m][tt]
  __shared__ __align__(16) float xpsT[128 * 4];     // [c][tt]  (xp, then a)
  __shared__ __align__(16) float xosT[128 * 4];     // [c][tt]  (x_o)
  __shared__ __align__(16) unsigned xo16[64 * 4];   // [p][tt] f16 pairs of sigma(xo)
  __shared__ __align__(16) unsigned ap16[64 * 4];   // [p][tt] f16 pairs of a
  __shared__ __align__(16) unsigned as16[64 * 4];   // [p][tt] f16 pairs of a^2

  const float* WinT = ws + OFF_WINT;
  const float* WT   = ws + OFF_WT;
  float* Xpre = ws + OFF_XPRE;
  float* aq   = ws + OFF_AQ;

  // stage x: 64 rows x 4 t's = 256 elems, 2 per thread
  #pragma unroll
  for (int k = 0; k < 2; ++k) {
    int idx = k * 128 + tid;
    int mm = idx >> 2, tt = idx & 3;
    xsT[mm * 4 + tt] = x[((size_t)b * MELN + mm) * TSN + t0 + tt];
  }
  __syncthreads();

  // xp rows: thread = output feature
  float acc4[4];
  {
    float bi = b_in[tid];
    #pragma unroll
    for (int j = 0; j < 4; ++j) acc4[j] = bi;
  }
  #pragma unroll 2
  for (int mI = 0; mI < MELN; ++mI) {
    float w = WinT[mI * 128 + tid];
    float4 xa = *(const float4*)&xsT[mI * 4];
    acc4[0] = fmaf(w, xa.x, acc4[0]); acc4[1] = fmaf(w, xa.y, acc4[1]);
    acc4[2] = fmaf(w, xa.z, acc4[2]); acc4[3] = fmaf(w, xa.w, acc4[3]);
  }
  *(float4*)&xpsT[tid * 4] = make_float4(acc4[0], acc4[1], acc4[2], acc4[3]);
  __syncthreads();

  // gate x-terms (ii,if,ig,io) + xo — full f32
  float accg[5][4];
  {
    float bsum[5];
    bsum[0] = b_ii[tid] + b_hi[tid];
    bsum[1] = b_if[tid] + b_hf[tid];
    bsum[2] = b_ig[tid] + b_hg[tid];
    bsum[3] = b_io[tid] + b_ho[tid];
    bsum[4] = b_xo[tid];
    #pragma unroll
    for (int g = 0; g < 5; ++g)
      #pragma unroll
      for (int j = 0; j < 4; ++j) accg[g][j] = bsum[g];
  }
  #pragma unroll 2
  for (int c = 0; c < 128; ++c) {
    const float4 xa = *(const float4*)&xpsT[c * 4];
    #pragma unroll
    for (int g = 0; g < 5; ++g) {
      const float w = WT[g * 16384 + c * 128 + tid];
      accg[g][0] = fmaf(w, xa.x, accg[g][0]);
      accg[g][1] = fmaf(w, xa.y, accg[g][1]);
      accg[g][2] = fmaf(w, xa.z, accg[g][2]);
      accg[g][3] = fmaf(w, xa.w, accg[g][3]);
    }
  }
  {
    size_t base = ((size_t)b * TSN + t0) * 512;
    #pragma unroll
    for (int tt = 0; tt < 4; ++tt)
      *(float4*)&Xpre[base + (size_t)tt * 512 + tid * 4] =
          make_float4(accg[0][tt], accg[1][tt], accg[2][tt], accg[3][tt]);
  }
  {
    #pragma unroll
    for (int tt = 0; tt < 4; ++tt) xosT[tid * 4 + tt] = sigm_p(accg[4][tt]);
  }
  __syncthreads();

  // pack sigma(xo) into f16 pairs along c: 64 p x 4 tt, 2 per thread
  {
    const int p = tid & 63;
    const int th = (tid >> 6) * 2;
    #pragma unroll
    for (int j = 0; j < 2; ++j) {
      const int tt = th + j;
      xo16[p * 4 + tt] = mku(xosT[(2 * p) * 4 + tt], xosT[(2 * p + 1) * 4 + tt]);
    }
  }
  __syncthreads();

  // q projection on x_o (f16 dot2) -> a = q / sqrt(H)
  float accq[4];
  {
    float bq = b_q[tid];
    #pragma unroll
    for (int j = 0; j < 4; ++j) accq[j] = bq;
  }
  const unsigned* WQ = (const unsigned*)(ws + OFF_WQ16);
  #pragma unroll 2
  for (int p = 0; p < 64; ++p) {
    const hf2 wq = u2h(WQ[p * 128 + tid]);
    const uint4 xa = *(const uint4*)&xo16[p * 4];
    accq[0] = dot2f(wq, u2h(xa.x), accq[0]);
    accq[1] = dot2f(wq, u2h(xa.y), accq[1]);
    accq[2] = dot2f(wq, u2h(xa.z), accq[2]);
    accq[3] = dot2f(wq, u2h(xa.w), accq[3]);
  }
  float av[4];
  #pragma unroll
  for (int tt = 0; tt < 4; ++tt) {
    av[tt] = accq[tt] * 0.08838834764831845f;
    aq[((size_t)b * TSN + t0 + tt) * 128 + tid] = av[tt];
  }

  // ---- A-moments (f16 dot2): A1 = W@a, A2 = W@a^2 for 4 gate matrices ----
  __syncthreads();   // gate/q phases' LDS reads complete
  *(float4*)&xpsT[tid * 4] = make_float4(av[0], av[1], av[2], av[3]);
  __syncthreads();
  {
    const int p = tid & 63;
    const int th = (tid >> 6) * 2;
    #pragma unroll
    for (int j = 0; j < 2; ++j) {
      const int tt = th + j;
      const float a0 = xpsT[(2 * p) * 4 + tt];
      const float a1 = xpsT[(2 * p + 1) * 4 + tt];
      ap16[p * 4 + tt] = mku(a0, a1);
      as16[p * 4 + tt] = mku(a0 * a0, a1 * a1);
    }
  }
  __syncthreads();
  float accA[4][4], accB[4][4];
  #pragma unroll
  for (int g = 0; g < 4; ++g)
    #pragma unroll
    for (int j = 0; j < 4; ++j) { accA[g][j] = 0.f; accB[g][j] = 0.f; }
  const unsigned* WH = (const unsigned*)(ws + OFF_WH16);
  #pragma unroll 2
  for (int p = 0; p < 64; ++p) {
    const uint4 aa = *(const uint4*)&ap16[p * 4];
    const uint4 sa = *(const uint4*)&as16[p * 4];
    #pragma unroll
    for (int g = 0; g < 4; ++g) {
      const hf2 w = u2h(WH[g * 8192 + p * 128 + tid]);
      accA[g][0] = dot2f(w, u2h(aa.x), accA[g][0]);
      accA[g][1] = dot2f(w, u2h(aa.y), accA[g][1]);
      accA[g][2] = dot2f(w, u2h(aa.z), accA[g][2]);
      accA[g][3] = dot2f(w, u2h(aa.w), accA[g][3]);
      accB[g][0] = dot2f(w, u2h(sa.x), accB[g][0]);
      accB[g][1] = dot2f(w, u2h(sa.y), accB[g][1]);
      accB[g][2] = dot2f(w, u2h(sa.z), accB[g][2]);
      accB[g][3] = dot2f(w, u2h(sa.w), accB[g][3]);
    }
  }
  {
    uint4* APre4 = (uint4*)(ws + OFF_APRE);
    #pragma unroll
    for (int tt = 0; tt < 4; ++tt) {
      uint4 u;
      u.x = pk2(accA[0][tt], accB[0][tt]);
      u.y = pk2(accA[1][tt], accB[1][tt]);
      u.z = pk2(accA[2][tt], accB[2][tt]);
      u.w = pk2(accA[3][tt], accB[3][tt]);
      APre4[((size_t)b * TSN + t0 + tt) * 128 + tid] = u;
    }
  }
}

// ---------------- P2: scan. 128 thr (2 waves); DPP reduce + distance-2 register prefetch.
// Barriers are lgkm-only (ldsbar) so prefetch global loads stay in flight across them. ----
__global__ __launch_bounds__(128, 1)
void k_scan(const float* __restrict__ W_k,  const float* __restrict__ b_k,
            const float* __restrict__ W_v,  const float* __restrict__ b_v,
            const float* __restrict__ W_ao, const float* __restrict__ b_ao,
            float* __restrict__ ws) {
  const int tid  = threadIdx.x;    // row 0..127
  const int lane = tid & 63;
  const int wid  = tid >> 6;       // wave 0..1
  const int b    = blockIdx.x;

  __shared__ __align__(16) _Float16 ch[128];     // c as f16 (direct b16 stores)
  __shared__ __align__(16) float part[16];       // [wave][moment 0..4] (stride 8)

  // full W_k row in registers as 64 f16 pairs (64 VGPRs)
  hf2 wkk2[64];
  #pragma unroll
  for (int p = 0; p < 64; ++p)
    wkk2[p] = mk2(W_k[(size_t)tid * 128 + 2 * p], W_k[(size_t)tid * 128 + 2 * p + 1]);
  const float bkr = b_k[tid];
  const float4 RSv = *(const float4*)&ws[OFF_RS + tid * 4];   // rowsums (ii,if,ig,io)

  // collapsed attention-output constants: h = s1*(attn.o) + s2
  float s1 = 0.f, s2 = 0.f;
  for (int j = 0; j < 128; ++j) {
    s1 = fmaf(W_ao[j], W_v[j], s1);
    s2 = fmaf(W_ao[j], b_v[j], s2);
  }
  s2 += b_ao[0];
  const float inv128 = 0.0078125f;
  const float s1i = s1 * inv128;

  const float* Xb = ws + OFF_XPRE + (size_t)b * TSN * 512;
  const float* ab = ws + OFF_AQ   + (size_t)b * TSN * 128;
  float*       Hb = ws + OFF_HALL + (size_t)b * TSN * 128;
  const uint4* APb = (const uint4*)(ws + OFF_APRE) + (size_t)b * TSN * 128;

  const uint4* c4u = (const uint4*)ch;

  // even/odd register sets (distance-2 prefetch; static names per rule #20)
  float4 X4e = *(const float4*)&Xb[tid * 4];                    // t=0
  float4 X4o = *(const float4*)&Xb[512 + tid * 4];              // t=1
  float  are = ab[tid];                                         // t=0
  float  aro = ab[128 + tid];                                   // t=1
  uint4  Ae  = APb[tid];   // dummy finite (t=0 has gamma=0)
  uint4  Ao  = APb[tid];   // A slot 0, used at t=1

  float c_reg = 0.f;
  float g0 = 0.f;                  // gamma0
  hf2   g12 = u2h(0u);             // (gamma1, gamma2) packed f16

#define SCAN_STEP(T, X4v, arv, Argv)                                          \
  {                                                                           \
    const float pi = dot2f(u2h((Argv).x), g12, fmaf(g0, RSv.x, (X4v).x));     \
    const float pf = dot2f(u2h((Argv).y), g12, fmaf(g0, RSv.y, (X4v).y));     \
    const float pg = dot2f(u2h((Argv).z), g12, fmaf(g0, RSv.z, (X4v).z));     \
    const float po = dot2f(u2h((Argv).w), g12, fmaf(g0, RSv.w, (X4v).w));     \
    /* early prefetch into this parity's regs (X,A last used above) */        \
    {                                                                         \
      const int tx = ((T) + 2 < TSN) ? (T) + 2 : TSN - 1;                     \
      (X4v) = *(const float4*)&Xb[(size_t)tx * 512 + tid * 4];                \
      const int ta = ((T) + 1 < TSN) ? (T) + 1 : TSN - 1;                     \
      (Argv) = APb[(size_t)ta * 128 + tid];                                   \
    }                                                                         \
    const float gi = sigm_f(pi);                                              \
    const float gf = sigm_f(pf);                                              \
    const float gg = tanh_f(pg);                                              \
    const float go = sigm_f(po);                                              \
    c_reg = fmaf(gf, c_reg, gi * gg);                                         \
    ch[tid] = (_Float16)c_reg;                                                \
    ldsbar();  /* [1] c visible (lgkm-only) */                                \
    float ka0 = 0.f, ka1 = 0.f, ka2 = 0.f, ka3 = 0.f;                         \
    _Pragma("unroll")                                                         \
    for (int u = 0; u < 16; ++u) {                                            \
      const uint4 cv = c4u[u];                                                \
      ka0 = dot2f(wkk2[u * 4 + 0], u2h(cv.x), ka0);                           \
      ka1 = dot2f(wkk2[u * 4 + 1], u2h(cv.y), ka1);                           \
      ka2 = dot2f(wkk2[u * 4 + 2], u2h(cv.z), ka2);                           \
      ka3 = dot2f(wkk2[u * 4 + 3], u2h(cv.w), ka3);                           \
    }                                                                         \
    const float kr = ((ka0 + ka1) + (ka2 + ka3)) + bkr;                       \
    const float kp2 = kr * kr;                                                \
    float m0 = kr, m1 = go, m2 = kp2, m3 = go * kr, m4 = go * kp2;            \
    m0 = wsum64(m0); m1 = wsum64(m1); m2 = wsum64(m2);                        \
    m3 = wsum64(m3); m4 = wsum64(m4);                                         \
    if (lane == 63) {                                                         \
      part[wid * 8 + 0] = m0; part[wid * 8 + 1] = m1;                         \
      part[wid * 8 + 2] = m2; part[wid * 8 + 3] = m3;                         \
      part[wid * 8 + 4] = m4;                                                 \
    }                                                                         \
    ldsbar();  /* [2] partials visible (lgkm-only) */                         \
    const float4 pa = *(const float4*)&part[0];                               \
    const float4 pb = *(const float4*)&part[8];                               \
    const float D1 = pa.x + pb.x;                                             \
    const float N0 = pa.y + pb.y;                                             \
    const float D2 = pa.z + pb.z;                                             \
    const float N1 = pa.w + pb.w;                                             \
    const float N2 = part[4] + part[12];                                      \
    const float t1 = D1 * inv128;                                             \
    g0 = fmaf(s1i, N0, s2);                                                   \
    const float gm1 = s1i * (N1 - N0 * t1);                                   \
    const float gm2 = s1i * (0.5f * N2 - (N1 * D1 + 0.5f * N0 * D2) * inv128  \
                             + N0 * t1 * t1);                                 \
    const float hn = fmaf(fmaf(gm2, (arv), gm1), (arv), g0);                  \
    Hb[(size_t)(T) * 128 + tid] = hn;                                         \
    g12 = u2h(pk2(gm1, gm2));                                                 \
    /* ar prefetch (distance-2, after last use) */                            \
    {                                                                         \
      const int tr = ((T) + 2 < TSN) ? (T) + 2 : TSN - 1;                     \
      (arv) = ab[(size_t)tr * 128 + tid];                                     \
    }                                                                         \
  }

  for (int k = 0; k < TSN / 2; ++k) {
    SCAN_STEP(2 * k,     X4e, are, Ae);
    SCAN_STEP(2 * k + 1, X4o, aro, Ao);
  }
#undef SCAN_STEP
}

// ---------------- P3: y = Hall @ W_out^T + b_out -> fp32 (B,C,T) ----------------
__global__ __launch_bounds__(256)
void k_out(const float* __restrict__ W_out, const float* __restrict__ b_out,
           const float* __restrict__ ws, float* __restrict__ out) {
  const int tid = threadIdx.x;
  const int b  = blockIdx.x >> 3;
  const int t0 = (blockIdx.x & 7) * 64;

  // stride 129 (odd): conflict-free read pattern
  __shared__ float Hs[64 * 129];

  const float* Hb = ws + OFF_HALL + ((size_t)b * TSN + t0) * 128;
  for (int k = 0; k < 32; ++k) {
    const int idx = k * 256 + tid;
    Hs[(idx >> 7) * 129 + (idx & 127)] = Hb[idx];
  }
  __syncthreads();

  const int tt = tid & 63;
  const int c0 = (tid >> 6) * 5;
  for (int j = 0; j < 5; ++j) {
    const int c = c0 + j;
    float s = b_out[c];
    for (int i = 0; i < 128; ++i)
      s = fmaf(Hs[tt * 129 + i], W_out[c * 128 + i], s);
    out[((size_t)b * CCN + c) * TSN + t0 + tt] = s;
  }
}

extern "C" void kernel_launch(void* const* d_in, const int* in_sizes, int n_in,
                              void* d_out, int out_size, void* d_ws, size_t ws_size,
                              hipStream_t stream) {
  const float* x    = (const float*)d_in[0];
  const float* W_in = (const float*)d_in[1];
  const float* b_in = (const float*)d_in[2];
  const float* W_out= (const float*)d_in[3];
  const float* b_out= (const float*)d_in[4];
  const float* W_ii = (const float*)d_in[5];
  const float* b_ii = (const float*)d_in[6];
  const float* W_hi = (const float*)d_in[7];
  const float* b_hi = (const float*)d_in[8];
  const float* W_if = (const float*)d_in[9];
  const float* b_if = (const float*)d_in[10];
  const float* W_hf = (const float*)d_in[11];
  const float* b_hf = (const float*)d_in[12];
  const float* W_ig = (const float*)d_in[13];
  const float* b_ig = (const float*)d_in[14];
  const float* W_hg = (const float*)d_in[15];
  const float* b_hg = (const float*)d_in[16];
  const float* W_io = (const float*)d_in[17];
  const float* b_io = (const float*)d_in[18];
  const float* W_ho = (const float*)d_in[19];
  const float* b_ho = (const float*)d_in[20];
  const float* W_xo = (const float*)d_in[21];
  const float* b_xo = (const float*)d_in[22];
  const float* W_q  = (const float*)d_in[23];
  const float* b_q  = (const float*)d_in[24];
  const float* W_k  = (const float*)d_in[25];
  const float* b_k  = (const float*)d_in[26];
  const float* W_v  = (const float*)d_in[27];
  const float* b_v  = (const float*)d_in[28];
  const float* W_ao = (const float*)d_in[29];
  const float* b_ao = (const float*)d_in[30];

  float* ws = (float*)d_ws;
  float* out = (float*)d_out;

  k_prep<<<12, 256, 0, stream>>>(W_in, W_ii, W_if, W_ig, W_io, W_xo, W_q,
                                 W_hi, W_hf, W_hg, W_ho, ws);
  k_xproj<<<BB * 128, 128, 0, stream>>>(x, b_in, b_ii, b_hi, b_if, b_hf, b_ig, b_hg,
                                        b_io, b_ho, b_xo, b_q, ws);
  k_scan<<<BB, 128, 0, stream>>>(W_k, b_k, W_v, b_v, W_ao, b_ao, ws);
  k_out<<<BB * 8, 256, 0, stream>>>(W_out, b_out, ws, out);
}